// Round 8
// baseline (772.400 us; speedup 1.0000x reference)
//
#include <hip/hip_runtime.h>

#define N_NODES 100000
#define N_EDGES 3200000
#define DIM 128
#define LN_EPS 1e-5f
#define NBLK 391              // ceil(N_NODES / 256)
#define N_BUCKETS 1563        // ceil(N_NODES / 64)
#define BUCKET_CAP 3072       // empirically verified bucket-count bound
#define SLAB_CAP 3072         // same bound for the global slab
#define PART_BLOCKS 800
#define PART_CHUNK 4000       // 800 * 4000 = 3.2M

// ---- tier-1 (slab) workspace layout (4-byte elements) ----
#define WS2_BCT   0           // int  [1600]  bucket counters
#define WS2_DIS   1600        // float[N_NODES]
#define WS2_LST   101600      // int  [100032] per-node exclusive starts
#define WS2_WB    201632      // 8192 ints (bf16 W)
#define WS2_XW    209824      // 6.4M ints (bf16 xW)
#define WS2_SLAB  6609824     // int [N_BUCKETS * SLAB_CAP]
#define WS_SLAB_BYTES ((size_t)(WS2_SLAB + N_BUCKETS * SLAB_CAP) * 4)

// ---- tier-2 (R7) workspace layout ----
#define WS_CNT    0           // int  [N_NODES]
#define WS_OFF    100000      // int  [N_NODES+1]
#define WS_DIS    200004      // float[N_NODES]
#define WS_BIN    300004      // int  [N_EDGES]
#define WS_BSUM   3500004     // int  [512]
#define WS_BEXC   3500516     // int  [512]
#define WS_BCUR   3501028     // int  [N_BUCKETS]
#define WS_WB     3502592     // 16384 bf16
#define WS_XW     3510784     // 12.8M bf16
#define WS_FUSED_BYTES ((size_t)(WS_XW + 6400000) * 4)

typedef __attribute__((ext_vector_type(8))) short short8;   // bf16x8 MFMA frag
typedef __attribute__((ext_vector_type(4))) float floatx4;  // MFMA acc

__device__ __forceinline__ short f2bf(float f) {
    unsigned u = __float_as_uint(f);
    unsigned r = (u + 0x7FFFu + ((u >> 16) & 1u)) >> 16;   // RNE
    return (short)r;
}
__device__ __forceinline__ float bf2f(unsigned short h) {
    return __uint_as_float(((unsigned)h) << 16);
}

// ================= tier-1: single-pass slab pipeline =================

// one pass over edges: direct placement into per-bucket slab
__global__ void __launch_bounds__(256) k_place(
        const int* __restrict__ row, const int* __restrict__ col,
        int* __restrict__ bktcnt, int* __restrict__ slab) {
    int e = (blockIdx.x * 256 + threadIdx.x) * 4;
    if (e >= N_EDGES) return;
    int4 r4 = *(const int4*)(row + e);
    int4 c4 = *(const int4*)(col + e);
    int b0 = c4.x >> 6, b1 = c4.y >> 6, b2 = c4.z >> 6, b3 = c4.w >> 6;
    int p0 = atomicAdd(&bktcnt[b0], 1);
    int p1 = atomicAdd(&bktcnt[b1], 1);
    int p2 = atomicAdd(&bktcnt[b2], 1);
    int p3 = atomicAdd(&bktcnt[b3], 1);
    slab[b0 * SLAB_CAP + p0] = r4.x | ((c4.x & 63) << 17);
    slab[b1 * SLAB_CAP + p1] = r4.y | ((c4.y & 63) << 17);
    slab[b2 * SLAB_CAP + p2] = r4.z | ((c4.z & 63) << 17);
    slab[b3 * SLAB_CAP + p3] = r4.w | ((c4.w & 63) << 17);
}

// per bucket: histogram -> degree (dis) + exclusive per-node starts (lstart)
__global__ void __launch_bounds__(256) k_meta(
        const int* __restrict__ slab, const int* __restrict__ bktcnt,
        float* __restrict__ dis, int* __restrict__ lstart) {
    __shared__ int h[64];
    int b = blockIdx.x;
    int tid = threadIdx.x;
    if (tid < 64) h[tid] = 0;
    __syncthreads();
    int nb = bktcnt[b];
    const int* sp = slab + (size_t)b * SLAB_CAP;
    for (int k = tid; k < nb; k += 256)
        atomicAdd(&h[sp[k] >> 17], 1);
    __syncthreads();
    if (tid < 64) {
        int deg = h[tid];
        int sc = deg;
#pragma unroll
        for (int d = 1; d < 64; d <<= 1) {
            int t = __shfl_up(sc, d, 64);
            if (tid >= d) sc += t;
        }
        lstart[(b << 6) + tid] = sc - deg;   // exclusive start
        int node = (b << 6) + tid;
        if (node < N_NODES) dis[node] = rsqrtf(1.0f + (float)deg);
    }
}

// gather: R7's verified body; prologue swapped to slab/lstart (no off[]).
__global__ void __launch_bounds__(512, 7) k_gather_slab(
        const unsigned short* __restrict__ xw,
        const float* __restrict__ dis,
        const int* __restrict__ slab,
        const int* __restrict__ bktcnt,
        const int* __restrict__ lstart,
        const float* __restrict__ bias,
        const float* __restrict__ gamma,
        const float* __restrict__ beta,
        float* __restrict__ out) {
    __shared__ int2 lpk[BUCKET_CAP + 16];
    __shared__ int lcur[64];
    int b = blockIdx.x;
    int node0 = b << 6;
    int tid = threadIdx.x;
    int nb = bktcnt[b];
    if (tid < 64) lcur[tid] = lstart[(b << 6) + tid];
    if (tid < 16) lpk[nb + tid] = make_int2(0, 0);   // zero pad for lookahead
    __syncthreads();

    const int* sp = slab + (size_t)b * SLAB_CAP;
    for (int k = tid; k < nb; k += 512) {
        int p = sp[k];
        int cl = p >> 17;
        int s = p & 0x1FFFF;
        float w = dis[s];
        int pos = atomicAdd(&lcur[cl], 1);
        lpk[pos] = make_int2(s, __float_as_int(w));
    }
    __syncthreads();
    // lcur[t] is now the END offset of node node0+t

    int wave = tid >> 6, lane = tid & 63;
    int half = lane >> 5;
    int hl = lane & 31;
    const unsigned* xwu = (const unsigned*)xw;
    const unsigned* xrow = xwu + 2 * hl;

#define ISSUE(bp_, end_, wR, uxR, uyR) do {                                     \
        _Pragma("unroll")                                                       \
        for (int t_ = 0; t_ < 4; ++t_) {                                        \
            int p_ = (bp_) + 2 * t_ + half;                                     \
            int2 e_ = lpk[p_];                                                  \
            wR[t_] = (p_ < (end_)) ? __int_as_float(e_.y) : 0.f;                \
            uint2 u_ = *(const uint2*)(xrow + (size_t)e_.x * 64);               \
            uxR[t_] = u_.x;                                                     \
            uyR[t_] = u_.y;                                                     \
        }                                                                       \
    } while (0)

#define CONSUME(wR, uxR, uyR) do {                                              \
        _Pragma("unroll")                                                       \
        for (int t_ = 0; t_ < 4; ++t_) {                                        \
            float w_ = wR[t_];                                                  \
            accx += w_ * __uint_as_float(uxR[t_] << 16);                        \
            accy += w_ * __uint_as_float(uxR[t_] & 0xffff0000u);                \
            accz += w_ * __uint_as_float(uyR[t_] << 16);                        \
            accw += w_ * __uint_as_float(uyR[t_] & 0xffff0000u);                \
        }                                                                       \
    } while (0)

    float wA[4], wB[4];
    unsigned uxA[4], uyA[4], uxB[4], uyB[4];

    for (int u = 0; u < 8; ++u) {
        int cl = wave * 8 + u;
        int node = node0 + cl;
        if (node >= N_NODES) break;
        int end = lcur[cl];
        int start = (cl == 0) ? 0 : lcur[cl - 1];

        float di = dis[node];
        uint2 udt = *(const uint2*)(xrow + (size_t)node * 64);

        float accx = 0.f, accy = 0.f, accz = 0.f, accw = 0.f;
        int bp = start;
        if (bp < end) {
            ISSUE(bp, end, wA, uxA, uyA);
            while (true) {
                if (bp + 8 < end) ISSUE(bp + 8, end, wB, uxB, uyB);
                CONSUME(wA, uxA, uyA);
                bp += 8;
                if (bp >= end) break;
                if (bp + 8 < end) ISSUE(bp + 8, end, wA, uxA, uyA);
                CONSUME(wB, uxB, uyB);
                bp += 8;
                if (bp >= end) break;
            }
        }

        accx += __shfl_xor(accx, 32, 64);
        accy += __shfl_xor(accy, 32, 64);
        accz += __shfl_xor(accz, 32, 64);
        accw += __shfl_xor(accw, 32, 64);

        float4 bi = ((const float4*)bias)[hl];
        float v0 = (accx + di * __uint_as_float(udt.x << 16)) * di + bi.x;
        float v1 = (accy + di * __uint_as_float(udt.x & 0xffff0000u)) * di + bi.y;
        float v2 = (accz + di * __uint_as_float(udt.y << 16)) * di + bi.z;
        float v3 = (accw + di * __uint_as_float(udt.y & 0xffff0000u)) * di + bi.w;

        float S = v0 + v1 + v2 + v3;
        float S2 = v0 * v0 + v1 * v1 + v2 * v2 + v3 * v3;
#pragma unroll
        for (int mask = 1; mask < 32; mask <<= 1) {
            S  += __shfl_xor(S,  mask, 64);
            S2 += __shfl_xor(S2, mask, 64);
        }
        float mean = S * (1.0f / DIM);
        float var  = S2 * (1.0f / DIM) - mean * mean;
        float inv  = rsqrtf(var + LN_EPS);
        float4 ga = ((const float4*)gamma)[hl];
        float4 be = ((const float4*)beta)[hl];
        float4 o;
        o.x = (v0 - mean) * inv * ga.x + be.x;
        o.y = (v1 - mean) * inv * ga.y + be.y;
        o.z = (v2 - mean) * inv * ga.z + be.z;
        o.w = (v3 - mean) * inv * ga.w + be.w;
        if (half == 0)
            ((float4*)out)[(size_t)node * 32 + hl] = o;
    }
#undef ISSUE
#undef CONSUME
}

// ================= tier-2: R7 pipeline (kept verbatim) =================

__global__ void k_count(const int* __restrict__ col, int* __restrict__ cnt) {
    int e = (blockIdx.x * blockDim.x + threadIdx.x) * 4;
    if (e < N_EDGES) {
        int4 c = *(const int4*)(col + e);
        atomicAdd(&cnt[c.x], 1);
        atomicAdd(&cnt[c.y], 1);
        atomicAdd(&cnt[c.z], 1);
        atomicAdd(&cnt[c.w], 1);
    }
}

__global__ void k_blockreduce(const int* __restrict__ cnt, int* __restrict__ bsum,
                              float* __restrict__ dis) {
    __shared__ int s[256];
    int i = blockIdx.x * 256 + threadIdx.x;
    int v = (i < N_NODES) ? cnt[i] : 0;
    if (i < N_NODES) dis[i] = rsqrtf(1.0f + (float)v);
    s[threadIdx.x] = v;
    __syncthreads();
    for (int st = 128; st > 0; st >>= 1) {
        if (threadIdx.x < st) s[threadIdx.x] += s[threadIdx.x + st];
        __syncthreads();
    }
    if (threadIdx.x == 0) bsum[blockIdx.x] = s[0];
}

__global__ void k_scanbsums(const int* __restrict__ bsum, int* __restrict__ bexc,
                            int* __restrict__ off) {
    __shared__ int s[512];
    int t = threadIdx.x;
    int v0 = (t < NBLK) ? bsum[t] : 0;
    s[t] = v0;
    __syncthreads();
    for (int st = 1; st < 512; st <<= 1) {
        int v = (t >= st) ? s[t - st] : 0;
        __syncthreads();
        s[t] += v;
        __syncthreads();
    }
    if (t < NBLK) bexc[t] = s[t] - v0;
    if (t == 0) off[N_NODES] = N_EDGES;
}

__global__ void k_blockscan(const int* __restrict__ cnt, const int* __restrict__ bexc,
                            int* __restrict__ off, int* __restrict__ bcur) {
    __shared__ int s[256];
    int i = blockIdx.x * 256 + threadIdx.x;
    int v = (i < N_NODES) ? cnt[i] : 0;
    s[threadIdx.x] = v;
    __syncthreads();
    for (int st = 1; st < 256; st <<= 1) {
        int u = (threadIdx.x >= st) ? s[threadIdx.x - st] : 0;
        __syncthreads();
        s[threadIdx.x] += u;
        __syncthreads();
    }
    if (i < N_NODES) {
        int o = bexc[blockIdx.x] + s[threadIdx.x] - v;
        off[i] = o;
        if ((i & 63) == 0) bcur[i >> 6] = o;
    }
}

__global__ void __launch_bounds__(256) k_binpack_staged(
        const int* __restrict__ row, const int* __restrict__ col,
        int* __restrict__ bcur, int* __restrict__ binned) {
    __shared__ int hist[N_BUCKETS];
    __shared__ int gpos[N_BUCKETS];
    int tid = threadIdx.x;
    int e0 = blockIdx.x * PART_CHUNK;
    int e1 = min(e0 + PART_CHUNK, N_EDGES);
    for (int t = tid; t < N_BUCKETS; t += 256) hist[t] = 0;
    __syncthreads();
    for (int e = e0 + tid; e < e1; e += 256)
        atomicAdd(&hist[col[e] >> 6], 1);
    __syncthreads();
    for (int t = tid; t < N_BUCKETS; t += 256) {
        int h = hist[t];
        gpos[t] = h ? atomicAdd(&bcur[t], h) : 0;
        hist[t] = 0;
    }
    __syncthreads();
    for (int e = e0 + tid; e < e1; e += 256) {
        int c = col[e];
        int b = c >> 6;
        int lp = atomicAdd(&hist[b], 1);
        binned[gpos[b] + lp] = row[e] | ((c & 63) << 17);
    }
}

__global__ void k_wconv(const float* __restrict__ W, short* __restrict__ Wb) {
    int i = blockIdx.x * 256 + threadIdx.x;
    if (i < DIM * DIM) Wb[i] = f2bf(W[i]);
}

__global__ void __launch_bounds__(256) k_xw(
        const float* __restrict__ x,
        const short* __restrict__ Wb,
        unsigned short* __restrict__ xw) {
    int wave = threadIdx.x >> 6;
    int lane = threadIdx.x & 63;
    int i0 = (blockIdx.x * 4 + wave) * 16;
    if (i0 >= N_NODES) return;
    int m = lane & 15;
    int q = lane >> 4;

    floatx4 acc[8];
#pragma unroll
    for (int t = 0; t < 8; ++t) acc[t] = (floatx4){0.f, 0.f, 0.f, 0.f};

#pragma unroll
    for (int s = 0; s < 4; ++s) {
        int k0 = s * 32 + q * 8;
        const float* ap = x + (size_t)(i0 + m) * DIM + k0;
        float4 a0 = *(const float4*)ap;
        float4 a1 = *(const float4*)(ap + 4);
        short8 af;
        af[0] = f2bf(a0.x); af[1] = f2bf(a0.y); af[2] = f2bf(a0.z); af[3] = f2bf(a0.w);
        af[4] = f2bf(a1.x); af[5] = f2bf(a1.y); af[6] = f2bf(a1.z); af[7] = f2bf(a1.w);
#pragma unroll
        for (int t = 0; t < 8; ++t) {
            short8 bf = *(const short8*)(Wb + (size_t)(t * 16 + m) * DIM + k0);
            acc[t] = __builtin_amdgcn_mfma_f32_16x16x32_bf16(af, bf, acc[t], 0, 0, 0);
        }
    }
#pragma unroll
    for (int r = 0; r < 4; ++r) {
        int node = i0 + q * 4 + r;
#pragma unroll
        for (int t = 0; t < 8; ++t)
            xw[(size_t)node * DIM + t * 16 + m] = (unsigned short)f2bf(acc[t][r]);
    }
}

__global__ void __launch_bounds__(512, 7) k_gather_fused(
        const unsigned short* __restrict__ xw,
        const float* __restrict__ dis,
        const int* __restrict__ binned,
        const int* __restrict__ off,
        const float* __restrict__ bias,
        const float* __restrict__ gamma,
        const float* __restrict__ beta,
        float* __restrict__ out) {
    __shared__ int2 lpk[BUCKET_CAP + 16];
    __shared__ int lcur[64];
    int b = blockIdx.x;
    int node0 = b << 6;
    int nt = min(64, N_NODES - node0);
    int tid = threadIdx.x;
    int base = off[node0];
    int cnt_b = off[node0 + nt] - base;
    if (tid < nt) lcur[tid] = off[node0 + tid] - base;
    if (tid < 16) lpk[cnt_b + tid] = make_int2(0, 0);
    __syncthreads();

    for (int k = tid; k < cnt_b; k += 512) {
        int p = binned[base + k];
        int cl = p >> 17;
        int s = p & 0x1FFFF;
        float w = dis[s];
        int pos = atomicAdd(&lcur[cl], 1);
        lpk[pos] = make_int2(s, __float_as_int(w));
    }
    __syncthreads();

    int wave = tid >> 6, lane = tid & 63;
    int half = lane >> 5;
    int hl = lane & 31;
    const unsigned* xwu = (const unsigned*)xw;
    const unsigned* xrow = xwu + 2 * hl;

#define ISSUE(bp_, end_, wR, uxR, uyR) do {                                     \
        _Pragma("unroll")                                                       \
        for (int t_ = 0; t_ < 4; ++t_) {                                        \
            int p_ = (bp_) + 2 * t_ + half;                                     \
            int2 e_ = lpk[p_];                                                  \
            wR[t_] = (p_ < (end_)) ? __int_as_float(e_.y) : 0.f;                \
            uint2 u_ = *(const uint2*)(xrow + (size_t)e_.x * 64);               \
            uxR[t_] = u_.x;                                                     \
            uyR[t_] = u_.y;                                                     \
        }                                                                       \
    } while (0)

#define CONSUME(wR, uxR, uyR) do {                                              \
        _Pragma("unroll")                                                       \
        for (int t_ = 0; t_ < 4; ++t_) {                                        \
            float w_ = wR[t_];                                                  \
            accx += w_ * __uint_as_float(uxR[t_] << 16);                        \
            accy += w_ * __uint_as_float(uxR[t_] & 0xffff0000u);                \
            accz += w_ * __uint_as_float(uyR[t_] << 16);                        \
            accw += w_ * __uint_as_float(uyR[t_] & 0xffff0000u);                \
        }                                                                       \
    } while (0)

    float wA[4], wB[4];
    unsigned uxA[4], uyA[4], uxB[4], uyB[4];

    for (int u = 0; u < 8; ++u) {
        int node = node0 + wave * 8 + u;
        if (node >= N_NODES) break;
        int start = off[node] - base, end = off[node + 1] - base;

        float di = dis[node];
        uint2 udt = *(const uint2*)(xrow + (size_t)node * 64);

        float accx = 0.f, accy = 0.f, accz = 0.f, accw = 0.f;
        int bp = start;
        if (bp < end) {
            ISSUE(bp, end, wA, uxA, uyA);
            while (true) {
                if (bp + 8 < end) ISSUE(bp + 8, end, wB, uxB, uyB);
                CONSUME(wA, uxA, uyA);
                bp += 8;
                if (bp >= end) break;
                if (bp + 8 < end) ISSUE(bp + 8, end, wA, uxA, uyA);
                CONSUME(wB, uxB, uyB);
                bp += 8;
                if (bp >= end) break;
            }
        }

        accx += __shfl_xor(accx, 32, 64);
        accy += __shfl_xor(accy, 32, 64);
        accz += __shfl_xor(accz, 32, 64);
        accw += __shfl_xor(accw, 32, 64);

        float4 bi = ((const float4*)bias)[hl];
        float v0 = (accx + di * __uint_as_float(udt.x << 16)) * di + bi.x;
        float v1 = (accy + di * __uint_as_float(udt.x & 0xffff0000u)) * di + bi.y;
        float v2 = (accz + di * __uint_as_float(udt.y << 16)) * di + bi.z;
        float v3 = (accw + di * __uint_as_float(udt.y & 0xffff0000u)) * di + bi.w;

        float S = v0 + v1 + v2 + v3;
        float S2 = v0 * v0 + v1 * v1 + v2 * v2 + v3 * v3;
#pragma unroll
        for (int mask = 1; mask < 32; mask <<= 1) {
            S  += __shfl_xor(S,  mask, 64);
            S2 += __shfl_xor(S2, mask, 64);
        }
        float mean = S * (1.0f / DIM);
        float var  = S2 * (1.0f / DIM) - mean * mean;
        float inv  = rsqrtf(var + LN_EPS);
        float4 ga = ((const float4*)gamma)[hl];
        float4 be = ((const float4*)beta)[hl];
        float4 o;
        o.x = (v0 - mean) * inv * ga.x + be.x;
        o.y = (v1 - mean) * inv * ga.y + be.y;
        o.z = (v2 - mean) * inv * ga.z + be.z;
        o.w = (v3 - mean) * inv * ga.w + be.w;
        if (half == 0)
            ((float4*)out)[(size_t)node * 32 + hl] = o;
    }
#undef ISSUE
#undef CONSUME
}

// ================= fallback path =================
__global__ void __launch_bounds__(256) k_bucket_gather(
        const float* __restrict__ x,
        const float* __restrict__ dis,
        const int* __restrict__ binned,
        const int* __restrict__ off,
        float* __restrict__ agg) {
    __shared__ int lcsr[BUCKET_CAP];
    __shared__ int lcur[64];
    int b = blockIdx.x;
    int node0 = b << 6;
    int nt = min(64, N_NODES - node0);
    int tid = threadIdx.x;
    int base = off[node0];
    int cnt_b = off[node0 + nt] - base;
    if (tid < nt) lcur[tid] = off[node0 + tid] - base;
    __syncthreads();
    for (int k = tid; k < cnt_b; k += 256) {
        int p = binned[base + k];
        int cl = p >> 17;
        int pos = atomicAdd(&lcur[cl], 1);
        lcsr[pos] = p & 0x1FFFF;
    }
    __syncthreads();
    int wave = tid >> 6, lane = tid & 63;
    const float2* x2 = (const float2*)x;
    for (int u = 0; u < 16; ++u) {
        int node = node0 + wave * 16 + u;
        if (node >= N_NODES) break;
        int start = off[node] - base, end = off[node + 1] - base;
        float2 acc = make_float2(0.f, 0.f);
        for (int bs = start; bs < end; bs += 64) {
            int n = min(64, end - bs);
            int s = 0;
            float w = 0.f;
            if (lane < n) { s = lcsr[bs + lane]; w = dis[s]; }
            for (int j = 0; j < n; ++j) {
                int sj = __shfl(s, j, 64);
                float wj = __shfl(w, j, 64);
                float2 xv = x2[(size_t)sj * 64 + lane];
                acc.x += wj * xv.x;
                acc.y += wj * xv.y;
            }
        }
        float di = dis[node];
        float2 xi = x2[(size_t)node * 64 + lane];
        acc.x = (acc.x + di * xi.x) * di;
        acc.y = (acc.y + di * xi.y) * di;
        ((float2*)agg)[(size_t)node * 64 + lane] = acc;
    }
}

__global__ void __launch_bounds__(256) k_linear_ln_mfma(
        const float* agg,
        const short* __restrict__ Wb,
        const float* __restrict__ bias,
        const float* __restrict__ gamma,
        const float* __restrict__ beta,
        float* out) {
    int wave = threadIdx.x >> 6;
    int lane = threadIdx.x & 63;
    int i0 = (blockIdx.x * 4 + wave) * 16;
    if (i0 >= N_NODES) return;
    int m = lane & 15;
    int q = lane >> 4;
    floatx4 acc[8];
#pragma unroll
    for (int t = 0; t < 8; ++t) acc[t] = (floatx4){0.f, 0.f, 0.f, 0.f};
#pragma unroll
    for (int s = 0; s < 4; ++s) {
        int k0 = s * 32 + q * 8;
        const float* ap = agg + (size_t)(i0 + m) * DIM + k0;
        float4 a0 = *(const float4*)ap;
        float4 a1 = *(const float4*)(ap + 4);
        short8 af;
        af[0] = f2bf(a0.x); af[1] = f2bf(a0.y); af[2] = f2bf(a0.z); af[3] = f2bf(a0.w);
        af[4] = f2bf(a1.x); af[5] = f2bf(a1.y); af[6] = f2bf(a1.z); af[7] = f2bf(a1.w);
#pragma unroll
        for (int t = 0; t < 8; ++t) {
            short8 bf = *(const short8*)(Wb + (size_t)(t * 16 + m) * DIM + k0);
            acc[t] = __builtin_amdgcn_mfma_f32_16x16x32_bf16(af, bf, acc[t], 0, 0, 0);
        }
    }
    float bv[8], gv[8], btv[8];
#pragma unroll
    for (int t = 0; t < 8; ++t) {
        int dim = t * 16 + m;
        bv[t] = bias[dim]; gv[t] = gamma[dim]; btv[t] = beta[dim];
    }
    float S[4], S2[4];
#pragma unroll
    for (int r = 0; r < 4; ++r) {
        float s = 0.f, s2 = 0.f;
#pragma unroll
        for (int t = 0; t < 8; ++t) {
            float v = acc[t][r] + bv[t];
            s += v; s2 += v * v;
        }
        S[r] = s; S2[r] = s2;
    }
#pragma unroll
    for (int mask = 1; mask < 16; mask <<= 1) {
#pragma unroll
        for (int r = 0; r < 4; ++r) {
            S[r]  += __shfl_xor(S[r],  mask, 64);
            S2[r] += __shfl_xor(S2[r], mask, 64);
        }
    }
#pragma unroll
    for (int r = 0; r < 4; ++r) {
        float mean = S[r] * (1.0f / DIM);
        float var  = S2[r] * (1.0f / DIM) - mean * mean;
        float inv  = rsqrtf(var + LN_EPS);
        int node = i0 + q * 4 + r;
#pragma unroll
        for (int t = 0; t < 8; ++t) {
            float v = acc[t][r] + bv[t];
            out[(size_t)node * DIM + t * 16 + m] = (v - mean) * inv * gv[t] + btv[t];
        }
    }
}

extern "C" void kernel_launch(void* const* d_in, const int* in_sizes, int n_in,
                              void* d_out, int out_size, void* d_ws, size_t ws_size,
                              hipStream_t stream) {
    const float* x     = (const float*)d_in[0];
    const int*   row   = (const int*)d_in[1];
    const int*   col   = ((const int*)d_in[1]) + N_EDGES;
    const float* W     = (const float*)d_in[2];
    const float* bias  = (const float*)d_in[3];
    const float* gamma = (const float*)d_in[4];
    const float* beta  = (const float*)d_in[5];
    float* out = (float*)d_out;

    int* wsi = (int*)d_ws;

    if (ws_size >= WS_SLAB_BYTES) {
        // tier-1: single-pass slab pipeline (6 launches)
        int*   bktcnt = wsi + WS2_BCT;
        float* dis    = (float*)(wsi + WS2_DIS);
        int*   lstart = wsi + WS2_LST;
        short* Wb     = (short*)(wsi + WS2_WB);
        unsigned short* xw = (unsigned short*)(wsi + WS2_XW);
        int*   slab   = wsi + WS2_SLAB;

        hipMemsetAsync(bktcnt, 0, N_BUCKETS * sizeof(int), stream);
        k_wconv<<<(DIM * DIM + 255) / 256, 256, 0, stream>>>(W, Wb);
        k_xw<<<(N_NODES / 16 + 3) / 4, 256, 0, stream>>>(x, Wb, xw);
        k_place<<<(N_EDGES / 4 + 255) / 256, 256, 0, stream>>>(row, col, bktcnt, slab);
        k_meta<<<N_BUCKETS, 256, 0, stream>>>(slab, bktcnt, dis, lstart);
        k_gather_slab<<<N_BUCKETS, 512, 0, stream>>>(
            xw, dis, slab, bktcnt, lstart, bias, gamma, beta, out);
        return;
    }

    int*   cnt    = wsi + WS_CNT;
    int*   off    = wsi + WS_OFF;
    float* dis    = (float*)(wsi + WS_DIS);
    int*   binned = wsi + WS_BIN;
    int*   bsum   = wsi + WS_BSUM;
    int*   bexc   = wsi + WS_BEXC;
    int*   bcur   = wsi + WS_BCUR;
    short* Wb     = (short*)(wsi + WS_WB);
    unsigned short* xw = (unsigned short*)(wsi + WS_XW);

    bool fused = ws_size >= WS_FUSED_BYTES;

    hipMemsetAsync(cnt, 0, N_NODES * sizeof(int), stream);

    k_wconv<<<(DIM * DIM + 255) / 256, 256, 0, stream>>>(W, Wb);
    if (fused)
        k_xw<<<(N_NODES / 16 + 3) / 4, 256, 0, stream>>>(x, Wb, xw);
    k_count<<<(N_EDGES / 4 + 255) / 256, 256, 0, stream>>>(col, cnt);
    k_blockreduce<<<NBLK, 256, 0, stream>>>(cnt, bsum, dis);
    k_scanbsums<<<1, 512, 0, stream>>>(bsum, bexc, off);
    k_blockscan<<<NBLK, 256, 0, stream>>>(cnt, bexc, off, bcur);
    k_binpack_staged<<<PART_BLOCKS, 256, 0, stream>>>(row, col, bcur, binned);

    if (fused) {
        k_gather_fused<<<N_BUCKETS, 512, 0, stream>>>(
            xw, dis, binned, off, bias, gamma, beta, out);
    } else {
        k_bucket_gather<<<N_BUCKETS, 256, 0, stream>>>(x, dis, binned, off, out);
        k_linear_ln_mfma<<<(N_NODES / 16 + 3) / 4, 256, 0, stream>>>(
            out, Wb, bias, gamma, beta, out);
    }
}

// Round 9
// 392.441 us; speedup vs baseline: 1.9682x; 1.9682x over previous
//
#include <hip/hip_runtime.h>

#define N_NODES 100000
#define N_EDGES 3200000
#define DIM 128
#define LN_EPS 1e-5f
#define NBLK 391              // ceil(N_NODES / 256)
#define N_BUCKETS 1563        // ceil(N_NODES / 64)
#define BUCKET_CAP 3072       // empirically verified bucket-count bound
#define SLAB_CAP 3072         // same bound for the global slab
#define PART_BLOCKS 800
#define PART_CHUNK 4000       // 800 * 4000 = 3.2M

// ---- tier-1 (slab) workspace layout (4-byte elements) ----
#define WS2_BCT   0           // int  [1600]  bucket counters
#define WS2_DIS   1600        // float[N_NODES]
#define WS2_LST   101600      // int  [100032] per-node exclusive starts
#define WS2_WB    201632      // 8192 ints (bf16 W)
#define WS2_XW    209824      // 6.4M ints (bf16 xW)
#define WS2_SLAB  6609824     // int [N_BUCKETS * SLAB_CAP]
#define WS_SLAB_BYTES ((size_t)(WS2_SLAB + N_BUCKETS * SLAB_CAP) * 4)

// ---- tier-2 (R7) workspace layout ----
#define WS_CNT    0           // int  [N_NODES]
#define WS_OFF    100000      // int  [N_NODES+1]
#define WS_DIS    200004      // float[N_NODES]
#define WS_BIN    300004      // int  [N_EDGES]
#define WS_BSUM   3500004     // int  [512]
#define WS_BEXC   3500516     // int  [512]
#define WS_BCUR   3501028     // int  [N_BUCKETS]
#define WS_WB     3502592     // 16384 bf16
#define WS_XW     3510784     // 12.8M bf16
#define WS_FUSED_BYTES ((size_t)(WS_XW + 6400000) * 4)

typedef __attribute__((ext_vector_type(8))) short short8;   // bf16x8 MFMA frag
typedef __attribute__((ext_vector_type(4))) float floatx4;  // MFMA acc

__device__ __forceinline__ short f2bf(float f) {
    unsigned u = __float_as_uint(f);
    unsigned r = (u + 0x7FFFu + ((u >> 16) & 1u)) >> 16;   // RNE
    return (short)r;
}
__device__ __forceinline__ float bf2f(unsigned short h) {
    return __uint_as_float(((unsigned)h) << 16);
}

// ================= tier-1: slab pipeline (6 launches) =================

// R9: LDS-staged placement (R7-verified k_binpack_staged body; slab target).
// R8's direct k_place serialized on 1563 hot counters (3.2M atomics, 477us,
// VALUBusy 0.17%). Per-block LDS hist -> one global atomicAdd per touched
// bucket per block -> ~0.9M well-spread atomics.
__global__ void __launch_bounds__(256) k_place_staged(
        const int* __restrict__ row, const int* __restrict__ col,
        int* __restrict__ bktcnt, int* __restrict__ slab) {
    __shared__ int hist[N_BUCKETS];
    __shared__ int gpos[N_BUCKETS];
    int tid = threadIdx.x;
    int e0 = blockIdx.x * PART_CHUNK;
    int e1 = min(e0 + PART_CHUNK, N_EDGES);
    for (int t = tid; t < N_BUCKETS; t += 256) hist[t] = 0;
    __syncthreads();
    for (int e = e0 + tid; e < e1; e += 256)
        atomicAdd(&hist[col[e] >> 6], 1);
    __syncthreads();
    for (int t = tid; t < N_BUCKETS; t += 256) {
        int h = hist[t];
        gpos[t] = h ? atomicAdd(&bktcnt[t], h) : 0;
        hist[t] = 0;
    }
    __syncthreads();
    for (int e = e0 + tid; e < e1; e += 256) {
        int c = col[e];
        int b = c >> 6;
        int lp = atomicAdd(&hist[b], 1);
        slab[(size_t)b * SLAB_CAP + gpos[b] + lp] = row[e] | ((c & 63) << 17);
    }
}

// per bucket: histogram -> degree (dis) + exclusive per-node starts (lstart)
__global__ void __launch_bounds__(256) k_meta(
        const int* __restrict__ slab, const int* __restrict__ bktcnt,
        float* __restrict__ dis, int* __restrict__ lstart) {
    __shared__ int h[64];
    int b = blockIdx.x;
    int tid = threadIdx.x;
    if (tid < 64) h[tid] = 0;
    __syncthreads();
    int nb = bktcnt[b];
    const int* sp = slab + (size_t)b * SLAB_CAP;
    for (int k = tid; k < nb; k += 256)
        atomicAdd(&h[sp[k] >> 17], 1);
    __syncthreads();
    if (tid < 64) {
        int deg = h[tid];
        int sc = deg;
#pragma unroll
        for (int d = 1; d < 64; d <<= 1) {
            int t = __shfl_up(sc, d, 64);
            if (tid >= d) sc += t;
        }
        lstart[(b << 6) + tid] = sc - deg;   // exclusive start
        int node = (b << 6) + tid;
        if (node < N_NODES) dis[node] = rsqrtf(1.0f + (float)deg);
    }
}

// gather: R7's verified body; prologue on slab/lstart (no off[]).
__global__ void __launch_bounds__(512, 7) k_gather_slab(
        const unsigned short* __restrict__ xw,
        const float* __restrict__ dis,
        const int* __restrict__ slab,
        const int* __restrict__ bktcnt,
        const int* __restrict__ lstart,
        const float* __restrict__ bias,
        const float* __restrict__ gamma,
        const float* __restrict__ beta,
        float* __restrict__ out) {
    __shared__ int2 lpk[BUCKET_CAP + 16];
    __shared__ int lcur[64];
    int b = blockIdx.x;
    int node0 = b << 6;
    int tid = threadIdx.x;
    int nb = bktcnt[b];
    if (tid < 64) lcur[tid] = lstart[(b << 6) + tid];
    if (tid < 16) lpk[nb + tid] = make_int2(0, 0);   // zero pad for lookahead
    __syncthreads();

    const int* sp = slab + (size_t)b * SLAB_CAP;
    for (int k = tid; k < nb; k += 512) {
        int p = sp[k];
        int cl = p >> 17;
        int s = p & 0x1FFFF;
        float w = dis[s];
        int pos = atomicAdd(&lcur[cl], 1);
        lpk[pos] = make_int2(s, __float_as_int(w));
    }
    __syncthreads();
    // lcur[t] is now the END offset of node node0+t

    int wave = tid >> 6, lane = tid & 63;
    int half = lane >> 5;
    int hl = lane & 31;
    const unsigned* xwu = (const unsigned*)xw;
    const unsigned* xrow = xwu + 2 * hl;

#define ISSUE(bp_, end_, wR, uxR, uyR) do {                                     \
        _Pragma("unroll")                                                       \
        for (int t_ = 0; t_ < 4; ++t_) {                                        \
            int p_ = (bp_) + 2 * t_ + half;                                     \
            int2 e_ = lpk[p_];                                                  \
            wR[t_] = (p_ < (end_)) ? __int_as_float(e_.y) : 0.f;                \
            uint2 u_ = *(const uint2*)(xrow + (size_t)e_.x * 64);               \
            uxR[t_] = u_.x;                                                     \
            uyR[t_] = u_.y;                                                     \
        }                                                                       \
    } while (0)

#define CONSUME(wR, uxR, uyR) do {                                              \
        _Pragma("unroll")                                                       \
        for (int t_ = 0; t_ < 4; ++t_) {                                        \
            float w_ = wR[t_];                                                  \
            accx += w_ * __uint_as_float(uxR[t_] << 16);                        \
            accy += w_ * __uint_as_float(uxR[t_] & 0xffff0000u);                \
            accz += w_ * __uint_as_float(uyR[t_] << 16);                        \
            accw += w_ * __uint_as_float(uyR[t_] & 0xffff0000u);                \
        }                                                                       \
    } while (0)

    float wA[4], wB[4];
    unsigned uxA[4], uyA[4], uxB[4], uyB[4];

    for (int u = 0; u < 8; ++u) {
        int cl = wave * 8 + u;
        int node = node0 + cl;
        if (node >= N_NODES) break;
        int end = lcur[cl];
        int start = (cl == 0) ? 0 : lcur[cl - 1];

        float di = dis[node];
        uint2 udt = *(const uint2*)(xrow + (size_t)node * 64);

        float accx = 0.f, accy = 0.f, accz = 0.f, accw = 0.f;
        int bp = start;
        if (bp < end) {
            ISSUE(bp, end, wA, uxA, uyA);
            while (true) {
                if (bp + 8 < end) ISSUE(bp + 8, end, wB, uxB, uyB);
                CONSUME(wA, uxA, uyA);
                bp += 8;
                if (bp >= end) break;
                if (bp + 8 < end) ISSUE(bp + 8, end, wA, uxA, uyA);
                CONSUME(wB, uxB, uyB);
                bp += 8;
                if (bp >= end) break;
            }
        }

        accx += __shfl_xor(accx, 32, 64);
        accy += __shfl_xor(accy, 32, 64);
        accz += __shfl_xor(accz, 32, 64);
        accw += __shfl_xor(accw, 32, 64);

        float4 bi = ((const float4*)bias)[hl];
        float v0 = (accx + di * __uint_as_float(udt.x << 16)) * di + bi.x;
        float v1 = (accy + di * __uint_as_float(udt.x & 0xffff0000u)) * di + bi.y;
        float v2 = (accz + di * __uint_as_float(udt.y << 16)) * di + bi.z;
        float v3 = (accw + di * __uint_as_float(udt.y & 0xffff0000u)) * di + bi.w;

        float S = v0 + v1 + v2 + v3;
        float S2 = v0 * v0 + v1 * v1 + v2 * v2 + v3 * v3;
#pragma unroll
        for (int mask = 1; mask < 32; mask <<= 1) {
            S  += __shfl_xor(S,  mask, 64);
            S2 += __shfl_xor(S2, mask, 64);
        }
        float mean = S * (1.0f / DIM);
        float var  = S2 * (1.0f / DIM) - mean * mean;
        float inv  = rsqrtf(var + LN_EPS);
        float4 ga = ((const float4*)gamma)[hl];
        float4 be = ((const float4*)beta)[hl];
        float4 o;
        o.x = (v0 - mean) * inv * ga.x + be.x;
        o.y = (v1 - mean) * inv * ga.y + be.y;
        o.z = (v2 - mean) * inv * ga.z + be.z;
        o.w = (v3 - mean) * inv * ga.w + be.w;
        if (half == 0)
            ((float4*)out)[(size_t)node * 32 + hl] = o;
    }
#undef ISSUE
#undef CONSUME
}

// ================= tier-2: R7 pipeline (kept verbatim) =================

__global__ void k_count(const int* __restrict__ col, int* __restrict__ cnt) {
    int e = (blockIdx.x * blockDim.x + threadIdx.x) * 4;
    if (e < N_EDGES) {
        int4 c = *(const int4*)(col + e);
        atomicAdd(&cnt[c.x], 1);
        atomicAdd(&cnt[c.y], 1);
        atomicAdd(&cnt[c.z], 1);
        atomicAdd(&cnt[c.w], 1);
    }
}

__global__ void k_blockreduce(const int* __restrict__ cnt, int* __restrict__ bsum,
                              float* __restrict__ dis) {
    __shared__ int s[256];
    int i = blockIdx.x * 256 + threadIdx.x;
    int v = (i < N_NODES) ? cnt[i] : 0;
    if (i < N_NODES) dis[i] = rsqrtf(1.0f + (float)v);
    s[threadIdx.x] = v;
    __syncthreads();
    for (int st = 128; st > 0; st >>= 1) {
        if (threadIdx.x < st) s[threadIdx.x] += s[threadIdx.x + st];
        __syncthreads();
    }
    if (threadIdx.x == 0) bsum[blockIdx.x] = s[0];
}

__global__ void k_scanbsums(const int* __restrict__ bsum, int* __restrict__ bexc,
                            int* __restrict__ off) {
    __shared__ int s[512];
    int t = threadIdx.x;
    int v0 = (t < NBLK) ? bsum[t] : 0;
    s[t] = v0;
    __syncthreads();
    for (int st = 1; st < 512; st <<= 1) {
        int v = (t >= st) ? s[t - st] : 0;
        __syncthreads();
        s[t] += v;
        __syncthreads();
    }
    if (t < NBLK) bexc[t] = s[t] - v0;
    if (t == 0) off[N_NODES] = N_EDGES;
}

__global__ void k_blockscan(const int* __restrict__ cnt, const int* __restrict__ bexc,
                            int* __restrict__ off, int* __restrict__ bcur) {
    __shared__ int s[256];
    int i = blockIdx.x * 256 + threadIdx.x;
    int v = (i < N_NODES) ? cnt[i] : 0;
    s[threadIdx.x] = v;
    __syncthreads();
    for (int st = 1; st < 256; st <<= 1) {
        int u = (threadIdx.x >= st) ? s[threadIdx.x - st] : 0;
        __syncthreads();
        s[threadIdx.x] += u;
        __syncthreads();
    }
    if (i < N_NODES) {
        int o = bexc[blockIdx.x] + s[threadIdx.x] - v;
        off[i] = o;
        if ((i & 63) == 0) bcur[i >> 6] = o;
    }
}

__global__ void __launch_bounds__(256) k_binpack_staged(
        const int* __restrict__ row, const int* __restrict__ col,
        int* __restrict__ bcur, int* __restrict__ binned) {
    __shared__ int hist[N_BUCKETS];
    __shared__ int gpos[N_BUCKETS];
    int tid = threadIdx.x;
    int e0 = blockIdx.x * PART_CHUNK;
    int e1 = min(e0 + PART_CHUNK, N_EDGES);
    for (int t = tid; t < N_BUCKETS; t += 256) hist[t] = 0;
    __syncthreads();
    for (int e = e0 + tid; e < e1; e += 256)
        atomicAdd(&hist[col[e] >> 6], 1);
    __syncthreads();
    for (int t = tid; t < N_BUCKETS; t += 256) {
        int h = hist[t];
        gpos[t] = h ? atomicAdd(&bcur[t], h) : 0;
        hist[t] = 0;
    }
    __syncthreads();
    for (int e = e0 + tid; e < e1; e += 256) {
        int c = col[e];
        int b = c >> 6;
        int lp = atomicAdd(&hist[b], 1);
        binned[gpos[b] + lp] = row[e] | ((c & 63) << 17);
    }
}

__global__ void k_wconv(const float* __restrict__ W, short* __restrict__ Wb) {
    int i = blockIdx.x * 256 + threadIdx.x;
    if (i < DIM * DIM) Wb[i] = f2bf(W[i]);
}

__global__ void __launch_bounds__(256) k_xw(
        const float* __restrict__ x,
        const short* __restrict__ Wb,
        unsigned short* __restrict__ xw) {
    int wave = threadIdx.x >> 6;
    int lane = threadIdx.x & 63;
    int i0 = (blockIdx.x * 4 + wave) * 16;
    if (i0 >= N_NODES) return;
    int m = lane & 15;
    int q = lane >> 4;

    floatx4 acc[8];
#pragma unroll
    for (int t = 0; t < 8; ++t) acc[t] = (floatx4){0.f, 0.f, 0.f, 0.f};

#pragma unroll
    for (int s = 0; s < 4; ++s) {
        int k0 = s * 32 + q * 8;
        const float* ap = x + (size_t)(i0 + m) * DIM + k0;
        float4 a0 = *(const float4*)ap;
        float4 a1 = *(const float4*)(ap + 4);
        short8 af;
        af[0] = f2bf(a0.x); af[1] = f2bf(a0.y); af[2] = f2bf(a0.z); af[3] = f2bf(a0.w);
        af[4] = f2bf(a1.x); af[5] = f2bf(a1.y); af[6] = f2bf(a1.z); af[7] = f2bf(a1.w);
#pragma unroll
        for (int t = 0; t < 8; ++t) {
            short8 bf = *(const short8*)(Wb + (size_t)(t * 16 + m) * DIM + k0);
            acc[t] = __builtin_amdgcn_mfma_f32_16x16x32_bf16(af, bf, acc[t], 0, 0, 0);
        }
    }
#pragma unroll
    for (int r = 0; r < 4; ++r) {
        int node = i0 + q * 4 + r;
#pragma unroll
        for (int t = 0; t < 8; ++t)
            xw[(size_t)node * DIM + t * 16 + m] = (unsigned short)f2bf(acc[t][r]);
    }
}

__global__ void __launch_bounds__(512, 7) k_gather_fused(
        const unsigned short* __restrict__ xw,
        const float* __restrict__ dis,
        const int* __restrict__ binned,
        const int* __restrict__ off,
        const float* __restrict__ bias,
        const float* __restrict__ gamma,
        const float* __restrict__ beta,
        float* __restrict__ out) {
    __shared__ int2 lpk[BUCKET_CAP + 16];
    __shared__ int lcur[64];
    int b = blockIdx.x;
    int node0 = b << 6;
    int nt = min(64, N_NODES - node0);
    int tid = threadIdx.x;
    int base = off[node0];
    int cnt_b = off[node0 + nt] - base;
    if (tid < nt) lcur[tid] = off[node0 + tid] - base;
    if (tid < 16) lpk[cnt_b + tid] = make_int2(0, 0);
    __syncthreads();

    for (int k = tid; k < cnt_b; k += 512) {
        int p = binned[base + k];
        int cl = p >> 17;
        int s = p & 0x1FFFF;
        float w = dis[s];
        int pos = atomicAdd(&lcur[cl], 1);
        lpk[pos] = make_int2(s, __float_as_int(w));
    }
    __syncthreads();

    int wave = tid >> 6, lane = tid & 63;
    int half = lane >> 5;
    int hl = lane & 31;
    const unsigned* xwu = (const unsigned*)xw;
    const unsigned* xrow = xwu + 2 * hl;

#define ISSUE(bp_, end_, wR, uxR, uyR) do {                                     \
        _Pragma("unroll")                                                       \
        for (int t_ = 0; t_ < 4; ++t_) {                                        \
            int p_ = (bp_) + 2 * t_ + half;                                     \
            int2 e_ = lpk[p_];                                                  \
            wR[t_] = (p_ < (end_)) ? __int_as_float(e_.y) : 0.f;                \
            uint2 u_ = *(const uint2*)(xrow + (size_t)e_.x * 64);               \
            uxR[t_] = u_.x;                                                     \
            uyR[t_] = u_.y;                                                     \
        }                                                                       \
    } while (0)

#define CONSUME(wR, uxR, uyR) do {                                              \
        _Pragma("unroll")                                                       \
        for (int t_ = 0; t_ < 4; ++t_) {                                        \
            float w_ = wR[t_];                                                  \
            accx += w_ * __uint_as_float(uxR[t_] << 16);                        \
            accy += w_ * __uint_as_float(uxR[t_] & 0xffff0000u);                \
            accz += w_ * __uint_as_float(uyR[t_] << 16);                        \
            accw += w_ * __uint_as_float(uyR[t_] & 0xffff0000u);                \
        }                                                                       \
    } while (0)

    float wA[4], wB[4];
    unsigned uxA[4], uyA[4], uxB[4], uyB[4];

    for (int u = 0; u < 8; ++u) {
        int node = node0 + wave * 8 + u;
        if (node >= N_NODES) break;
        int start = off[node] - base, end = off[node + 1] - base;

        float di = dis[node];
        uint2 udt = *(const uint2*)(xrow + (size_t)node * 64);

        float accx = 0.f, accy = 0.f, accz = 0.f, accw = 0.f;
        int bp = start;
        if (bp < end) {
            ISSUE(bp, end, wA, uxA, uyA);
            while (true) {
                if (bp + 8 < end) ISSUE(bp + 8, end, wB, uxB, uyB);
                CONSUME(wA, uxA, uyA);
                bp += 8;
                if (bp >= end) break;
                if (bp + 8 < end) ISSUE(bp + 8, end, wA, uxA, uyA);
                CONSUME(wB, uxB, uyB);
                bp += 8;
                if (bp >= end) break;
            }
        }

        accx += __shfl_xor(accx, 32, 64);
        accy += __shfl_xor(accy, 32, 64);
        accz += __shfl_xor(accz, 32, 64);
        accw += __shfl_xor(accw, 32, 64);

        float4 bi = ((const float4*)bias)[hl];
        float v0 = (accx + di * __uint_as_float(udt.x << 16)) * di + bi.x;
        float v1 = (accy + di * __uint_as_float(udt.x & 0xffff0000u)) * di + bi.y;
        float v2 = (accz + di * __uint_as_float(udt.y << 16)) * di + bi.z;
        float v3 = (accw + di * __uint_as_float(udt.y & 0xffff0000u)) * di + bi.w;

        float S = v0 + v1 + v2 + v3;
        float S2 = v0 * v0 + v1 * v1 + v2 * v2 + v3 * v3;
#pragma unroll
        for (int mask = 1; mask < 32; mask <<= 1) {
            S  += __shfl_xor(S,  mask, 64);
            S2 += __shfl_xor(S2, mask, 64);
        }
        float mean = S * (1.0f / DIM);
        float var  = S2 * (1.0f / DIM) - mean * mean;
        float inv  = rsqrtf(var + LN_EPS);
        float4 ga = ((const float4*)gamma)[hl];
        float4 be = ((const float4*)beta)[hl];
        float4 o;
        o.x = (v0 - mean) * inv * ga.x + be.x;
        o.y = (v1 - mean) * inv * ga.y + be.y;
        o.z = (v2 - mean) * inv * ga.z + be.z;
        o.w = (v3 - mean) * inv * ga.w + be.w;
        if (half == 0)
            ((float4*)out)[(size_t)node * 32 + hl] = o;
    }
#undef ISSUE
#undef CONSUME
}

// ================= fallback path =================
__global__ void __launch_bounds__(256) k_bucket_gather(
        const float* __restrict__ x,
        const float* __restrict__ dis,
        const int* __restrict__ binned,
        const int* __restrict__ off,
        float* __restrict__ agg) {
    __shared__ int lcsr[BUCKET_CAP];
    __shared__ int lcur[64];
    int b = blockIdx.x;
    int node0 = b << 6;
    int nt = min(64, N_NODES - node0);
    int tid = threadIdx.x;
    int base = off[node0];
    int cnt_b = off[node0 + nt] - base;
    if (tid < nt) lcur[tid] = off[node0 + tid] - base;
    __syncthreads();
    for (int k = tid; k < cnt_b; k += 256) {
        int p = binned[base + k];
        int cl = p >> 17;
        int pos = atomicAdd(&lcur[cl], 1);
        lcsr[pos] = p & 0x1FFFF;
    }
    __syncthreads();
    int wave = tid >> 6, lane = tid & 63;
    const float2* x2 = (const float2*)x;
    for (int u = 0; u < 16; ++u) {
        int node = node0 + wave * 16 + u;
        if (node >= N_NODES) break;
        int start = off[node] - base, end = off[node + 1] - base;
        float2 acc = make_float2(0.f, 0.f);
        for (int bs = start; bs < end; bs += 64) {
            int n = min(64, end - bs);
            int s = 0;
            float w = 0.f;
            if (lane < n) { s = lcsr[bs + lane]; w = dis[s]; }
            for (int j = 0; j < n; ++j) {
                int sj = __shfl(s, j, 64);
                float wj = __shfl(w, j, 64);
                float2 xv = x2[(size_t)sj * 64 + lane];
                acc.x += wj * xv.x;
                acc.y += wj * xv.y;
            }
        }
        float di = dis[node];
        float2 xi = x2[(size_t)node * 64 + lane];
        acc.x = (acc.x + di * xi.x) * di;
        acc.y = (acc.y + di * xi.y) * di;
        ((float2*)agg)[(size_t)node * 64 + lane] = acc;
    }
}

__global__ void __launch_bounds__(256) k_linear_ln_mfma(
        const float* agg,
        const short* __restrict__ Wb,
        const float* __restrict__ bias,
        const float* __restrict__ gamma,
        const float* __restrict__ beta,
        float* out) {
    int wave = threadIdx.x >> 6;
    int lane = threadIdx.x & 63;
    int i0 = (blockIdx.x * 4 + wave) * 16;
    if (i0 >= N_NODES) return;
    int m = lane & 15;
    int q = lane >> 4;
    floatx4 acc[8];
#pragma unroll
    for (int t = 0; t < 8; ++t) acc[t] = (floatx4){0.f, 0.f, 0.f, 0.f};
#pragma unroll
    for (int s = 0; s < 4; ++s) {
        int k0 = s * 32 + q * 8;
        const float* ap = agg + (size_t)(i0 + m) * DIM + k0;
        float4 a0 = *(const float4*)ap;
        float4 a1 = *(const float4*)(ap + 4);
        short8 af;
        af[0] = f2bf(a0.x); af[1] = f2bf(a0.y); af[2] = f2bf(a0.z); af[3] = f2bf(a0.w);
        af[4] = f2bf(a1.x); af[5] = f2bf(a1.y); af[6] = f2bf(a1.z); af[7] = f2bf(a1.w);
#pragma unroll
        for (int t = 0; t < 8; ++t) {
            short8 bf = *(const short8*)(Wb + (size_t)(t * 16 + m) * DIM + k0);
            acc[t] = __builtin_amdgcn_mfma_f32_16x16x32_bf16(af, bf, acc[t], 0, 0, 0);
        }
    }
    float bv[8], gv[8], btv[8];
#pragma unroll
    for (int t = 0; t < 8; ++t) {
        int dim = t * 16 + m;
        bv[t] = bias[dim]; gv[t] = gamma[dim]; btv[t] = beta[dim];
    }
    float S[4], S2[4];
#pragma unroll
    for (int r = 0; r < 4; ++r) {
        float s = 0.f, s2 = 0.f;
#pragma unroll
        for (int t = 0; t < 8; ++t) {
            float v = acc[t][r] + bv[t];
            s += v; s2 += v * v;
        }
        S[r] = s; S2[r] = s2;
    }
#pragma unroll
    for (int mask = 1; mask < 16; mask <<= 1) {
#pragma unroll
        for (int r = 0; r < 4; ++r) {
            S[r]  += __shfl_xor(S[r],  mask, 64);
            S2[r] += __shfl_xor(S2[r], mask, 64);
        }
    }
#pragma unroll
    for (int r = 0; r < 4; ++r) {
        float mean = S[r] * (1.0f / DIM);
        float var  = S2[r] * (1.0f / DIM) - mean * mean;
        float inv  = rsqrtf(var + LN_EPS);
        int node = i0 + q * 4 + r;
#pragma unroll
        for (int t = 0; t < 8; ++t) {
            float v = acc[t][r] + bv[t];
            out[(size_t)node * DIM + t * 16 + m] = (v - mean) * inv * gv[t] + btv[t];
        }
    }
}

extern "C" void kernel_launch(void* const* d_in, const int* in_sizes, int n_in,
                              void* d_out, int out_size, void* d_ws, size_t ws_size,
                              hipStream_t stream) {
    const float* x     = (const float*)d_in[0];
    const int*   row   = (const int*)d_in[1];
    const int*   col   = ((const int*)d_in[1]) + N_EDGES;
    const float* W     = (const float*)d_in[2];
    const float* bias  = (const float*)d_in[3];
    const float* gamma = (const float*)d_in[4];
    const float* beta  = (const float*)d_in[5];
    float* out = (float*)d_out;

    int* wsi = (int*)d_ws;

    if (ws_size >= WS_SLAB_BYTES) {
        // tier-1: slab pipeline (6 launches, no scan cascade)
        int*   bktcnt = wsi + WS2_BCT;
        float* dis    = (float*)(wsi + WS2_DIS);
        int*   lstart = wsi + WS2_LST;
        short* Wb     = (short*)(wsi + WS2_WB);
        unsigned short* xw = (unsigned short*)(wsi + WS2_XW);
        int*   slab   = wsi + WS2_SLAB;

        hipMemsetAsync(bktcnt, 0, N_BUCKETS * sizeof(int), stream);
        k_wconv<<<(DIM * DIM + 255) / 256, 256, 0, stream>>>(W, Wb);
        k_xw<<<(N_NODES / 16 + 3) / 4, 256, 0, stream>>>(x, Wb, xw);
        k_place_staged<<<PART_BLOCKS, 256, 0, stream>>>(row, col, bktcnt, slab);
        k_meta<<<N_BUCKETS, 256, 0, stream>>>(slab, bktcnt, dis, lstart);
        k_gather_slab<<<N_BUCKETS, 512, 0, stream>>>(
            xw, dis, slab, bktcnt, lstart, bias, gamma, beta, out);
        return;
    }

    int*   cnt    = wsi + WS_CNT;
    int*   off    = wsi + WS_OFF;
    float* dis    = (float*)(wsi + WS_DIS);
    int*   binned = wsi + WS_BIN;
    int*   bsum   = wsi + WS_BSUM;
    int*   bexc   = wsi + WS_BEXC;
    int*   bcur   = wsi + WS_BCUR;
    short* Wb     = (short*)(wsi + WS_WB);
    unsigned short* xw = (unsigned short*)(wsi + WS_XW);

    bool fused = ws_size >= WS_FUSED_BYTES;

    hipMemsetAsync(cnt, 0, N_NODES * sizeof(int), stream);

    k_wconv<<<(DIM * DIM + 255) / 256, 256, 0, stream>>>(W, Wb);
    if (fused)
        k_xw<<<(N_NODES / 16 + 3) / 4, 256, 0, stream>>>(x, Wb, xw);
    k_count<<<(N_EDGES / 4 + 255) / 256, 256, 0, stream>>>(col, cnt);
    k_blockreduce<<<NBLK, 256, 0, stream>>>(cnt, bsum, dis);
    k_scanbsums<<<1, 512, 0, stream>>>(bsum, bexc, off);
    k_blockscan<<<NBLK, 256, 0, stream>>>(cnt, bexc, off, bcur);
    k_binpack_staged<<<PART_BLOCKS, 256, 0, stream>>>(row, col, bcur, binned);

    if (fused) {
        k_gather_fused<<<N_BUCKETS, 512, 0, stream>>>(
            xw, dis, binned, off, bias, gamma, beta, out);
    } else {
        k_bucket_gather<<<N_BUCKETS, 256, 0, stream>>>(x, dis, binned, off, out);
        k_linear_ln_mfma<<<(N_NODES / 16 + 3) / 4, 256, 0, stream>>>(
            out, Wb, bias, gamma, beta, out);
    }
}